// Round 1
// baseline (1736.851 us; speedup 1.0000x reference)
//
#include <hip/hip_runtime.h>
#include <math.h>

// Problem constants
constexpr int Bc   = 2;
constexpr int Sc   = 4096;
constexpr int HIDc = 768;
constexpr int Hc   = 12;
constexpr int Dc   = 64;
constexpr int Wc   = 128;     // band half-width
constexpr int NBc  = 2*Wc + 1; // 257 band offsets
constexpr int Mc   = Bc * Sc; // 8192 rows

// attention tiling
constexpr int QT    = 32;            // queries per block
constexpr int KROWS = QT + 2*Wc;     // 288 staged key rows
constexpr int LDK   = 65;            // padded row stride (bank-conflict-free)

// ---------------------------------------------------------------------------
// Fused QKV projection: out = (x @ W + b) [* 0.125 for q], layout [B,H,S,D]
// 128x128 tile, BK=16, 8x8 per thread, fp32.
// ---------------------------------------------------------------------------
__global__ __launch_bounds__(256) void gemm_qkv(
    const float* __restrict__ x,
    const float* __restrict__ Wq, const float* __restrict__ bq,
    const float* __restrict__ Wk, const float* __restrict__ bk,
    const float* __restrict__ Wv, const float* __restrict__ bv,
    float* __restrict__ qg, float* __restrict__ kg, float* __restrict__ vg)
{
    const int z = blockIdx.z;
    const float* Wm   = (z == 0) ? Wq : (z == 1) ? Wk : Wv;
    const float* bias = (z == 0) ? bq : (z == 1) ? bk : bv;
    float* outp       = (z == 0) ? qg : (z == 1) ? kg : vg;
    const float scale = (z == 0) ? 0.125f : 1.0f;  // 1/sqrt(64)

    __shared__ float As[16][132];  // As[kk][row]  (A transposed into LDS)
    __shared__ float Bs[16][132];  // Bs[kk][col]

    const int tid = threadIdx.x;
    const int tx = tid & 15, ty = tid >> 4;
    const int m0 = blockIdx.x * 128;
    const int n0 = blockIdx.y * 128;

    float acc[8][8];
#pragma unroll
    for (int i = 0; i < 8; ++i)
#pragma unroll
        for (int j = 0; j < 8; ++j) acc[i][j] = 0.f;

    for (int k0 = 0; k0 < HIDc; k0 += 16) {
        __syncthreads();
        // A tile: 128 rows x 16 k
#pragma unroll
        for (int l = 0; l < 2; ++l) {
            int q = tid + l * 256;          // 0..511 float4s
            int row = q >> 2, kc = (q & 3) * 4;
            float4 v4 = *(const float4*)&x[(size_t)(m0 + row) * HIDc + k0 + kc];
            As[kc + 0][row] = v4.x; As[kc + 1][row] = v4.y;
            As[kc + 2][row] = v4.z; As[kc + 3][row] = v4.w;
        }
        // B tile: 16 k x 128 cols
#pragma unroll
        for (int l = 0; l < 2; ++l) {
            int q = tid + l * 256;
            int kr = q >> 5, nc = (q & 31) * 4;
            *(float4*)&Bs[kr][nc] = *(const float4*)&Wm[(size_t)(k0 + kr) * HIDc + n0 + nc];
        }
        __syncthreads();
#pragma unroll
        for (int kk = 0; kk < 16; ++kk) {
            float a[8], b[8];
            *(float4*)&a[0] = *(const float4*)&As[kk][ty * 8];
            *(float4*)&a[4] = *(const float4*)&As[kk][ty * 8 + 4];
            *(float4*)&b[0] = *(const float4*)&Bs[kk][tx * 8];
            *(float4*)&b[4] = *(const float4*)&Bs[kk][tx * 8 + 4];
#pragma unroll
            for (int i = 0; i < 8; ++i)
#pragma unroll
                for (int j = 0; j < 8; ++j)
                    acc[i][j] = fmaf(a[i], b[j], acc[i][j]);
        }
    }
    // epilogue: scatter to [B,H,S,D]
#pragma unroll
    for (int i = 0; i < 8; ++i) {
        int m = m0 + ty * 8 + i;
        int b = m >> 12;             // m / S
        int s = m & (Sc - 1);
#pragma unroll
        for (int j = 0; j < 8; ++j) {
            int n = n0 + tx * 8 + j;
            int h = n >> 6, d = n & 63;
            outp[(((size_t)(b * Hc + h)) * Sc + s) * Dc + d] =
                (acc[i][j] + bias[n]) * scale;
        }
    }
}

// ---------------------------------------------------------------------------
// Output projection + residual: y = ctx @ Wd + bd + x   (y in [M, HID])
// ---------------------------------------------------------------------------
__global__ __launch_bounds__(256) void gemm_proj(
    const float* __restrict__ A,   // ctx [M, HID]
    const float* __restrict__ Wd,  // [HID, HID] (H*D flattened rows)
    const float* __restrict__ bd,
    const float* __restrict__ x,
    float* __restrict__ y)
{
    __shared__ float As[16][132];
    __shared__ float Bs[16][132];

    const int tid = threadIdx.x;
    const int tx = tid & 15, ty = tid >> 4;
    const int m0 = blockIdx.x * 128;
    const int n0 = blockIdx.y * 128;

    float acc[8][8];
#pragma unroll
    for (int i = 0; i < 8; ++i)
#pragma unroll
        for (int j = 0; j < 8; ++j) acc[i][j] = 0.f;

    for (int k0 = 0; k0 < HIDc; k0 += 16) {
        __syncthreads();
#pragma unroll
        for (int l = 0; l < 2; ++l) {
            int q = tid + l * 256;
            int row = q >> 2, kc = (q & 3) * 4;
            float4 v4 = *(const float4*)&A[(size_t)(m0 + row) * HIDc + k0 + kc];
            As[kc + 0][row] = v4.x; As[kc + 1][row] = v4.y;
            As[kc + 2][row] = v4.z; As[kc + 3][row] = v4.w;
        }
#pragma unroll
        for (int l = 0; l < 2; ++l) {
            int q = tid + l * 256;
            int kr = q >> 5, nc = (q & 31) * 4;
            *(float4*)&Bs[kr][nc] = *(const float4*)&Wd[(size_t)(k0 + kr) * HIDc + n0 + nc];
        }
        __syncthreads();
#pragma unroll
        for (int kk = 0; kk < 16; ++kk) {
            float a[8], b[8];
            *(float4*)&a[0] = *(const float4*)&As[kk][ty * 8];
            *(float4*)&a[4] = *(const float4*)&As[kk][ty * 8 + 4];
            *(float4*)&b[0] = *(const float4*)&Bs[kk][tx * 8];
            *(float4*)&b[4] = *(const float4*)&Bs[kk][tx * 8 + 4];
#pragma unroll
            for (int i = 0; i < 8; ++i)
#pragma unroll
                for (int j = 0; j < 8; ++j)
                    acc[i][j] = fmaf(a[i], b[j], acc[i][j]);
        }
    }
#pragma unroll
    for (int i = 0; i < 8; ++i) {
        int m = m0 + ty * 8 + i;
#pragma unroll
        for (int j = 0; j < 8; ++j) {
            int n = n0 + tx * 8 + j;
            size_t idx = (size_t)m * HIDc + n;
            y[idx] = acc[i][j] + bd[n] + x[idx];
        }
    }
}

// ---------------------------------------------------------------------------
// Banded attention: block = (query-tile of 32, head, batch).
// LDS: qs[32][65] + ss[32][257] + kv[288][65]  = 116096 B (dynamic)
// ---------------------------------------------------------------------------
__global__ __launch_bounds__(256) void band_attn(
    const float* __restrict__ qg, const float* __restrict__ kg,
    const float* __restrict__ vg, float* __restrict__ ctx)
{
    extern __shared__ float lds[];
    float* qs = lds;                    // [QT][LDK]
    float* ss = qs + QT * LDK;          // [QT][NBc]
    float* kv = ss + QT * NBc;          // [KROWS][LDK]

    const int qc = blockIdx.x, h = blockIdx.y, b = blockIdx.z;
    const int s0 = qc * QT;
    const int tid = threadIdx.x;
    const size_t headbase = ((size_t)(b * Hc + h)) * Sc * Dc;

    // load Q tile (32x64 = 512 float4)
#pragma unroll
    for (int l = 0; l < 2; ++l) {
        int q = tid + l * 256;
        int row = q >> 4, dc = (q & 15) * 4;
        float4 v4 = *(const float4*)&qg[headbase + (size_t)(s0 + row) * Dc + dc];
        qs[row * LDK + dc + 0] = v4.x; qs[row * LDK + dc + 1] = v4.y;
        qs[row * LDK + dc + 2] = v4.z; qs[row * LDK + dc + 3] = v4.w;
    }
    // load K window rows 0..287 (pos = s0 - W + row), OOB -> 0
#pragma unroll
    for (int l = 0; l < 18; ++l) {
        int q = tid + l * 256;          // 0..4607 float4s
        int row = q >> 4, dc = (q & 15) * 4;
        int pos = s0 - Wc + row;
        float4 v4 = make_float4(0.f, 0.f, 0.f, 0.f);
        if (pos >= 0 && pos < Sc)
            v4 = *(const float4*)&kg[headbase + (size_t)pos * Dc + dc];
        kv[row * LDK + dc + 0] = v4.x; kv[row * LDK + dc + 1] = v4.y;
        kv[row * LDK + dc + 2] = v4.z; kv[row * LDK + dc + 3] = v4.w;
    }
    __syncthreads();

    // phase 1: scores  ss[qi][j] = q_i . k_{i+j-W}  (or -1e9 if OOB)
    for (int e = tid; e < QT * NBc; e += 256) {
        int qi = e / NBc;
        int j  = e - qi * NBc;
        int pos = s0 - Wc + qi + j;
        const float* qrow = &qs[qi * LDK];
        const float* krow = &kv[(qi + j) * LDK];
        float dot = 0.f;
#pragma unroll
        for (int d = 0; d < Dc; ++d) dot = fmaf(qrow[d], krow[d], dot);
        ss[qi * NBc + j] = (pos >= 0 && pos < Sc) ? dot : -1e9f;
    }
    __syncthreads();

    // reload window with V (ss-only phase 2 may interleave; kv free now)
#pragma unroll
    for (int l = 0; l < 18; ++l) {
        int q = tid + l * 256;
        int row = q >> 4, dc = (q & 15) * 4;
        int pos = s0 - Wc + row;
        float4 v4 = make_float4(0.f, 0.f, 0.f, 0.f);
        if (pos >= 0 && pos < Sc)
            v4 = *(const float4*)&vg[headbase + (size_t)pos * Dc + dc];
        kv[row * LDK + dc + 0] = v4.x; kv[row * LDK + dc + 1] = v4.y;
        kv[row * LDK + dc + 2] = v4.z; kv[row * LDK + dc + 3] = v4.w;
    }

    // phase 2: softmax (4 waves x 8 rows) — touches only ss
    {
        const int wid = tid >> 6, lane = tid & 63;
        for (int row = wid; row < QT; row += 4) {
            float* sr = &ss[row * NBc];
            float mx = -1e30f;
            for (int i = lane; i < NBc; i += 64) mx = fmaxf(mx, sr[i]);
#pragma unroll
            for (int o = 1; o < 64; o <<= 1) mx = fmaxf(mx, __shfl_xor(mx, o));
            float sum = 0.f;
            for (int i = lane; i < NBc; i += 64) {
                float e = __expf(sr[i] - mx);
                sr[i] = e;
                sum += e;
            }
#pragma unroll
            for (int o = 1; o < 64; o <<= 1) sum += __shfl_xor(sum, o);
            float inv = 1.f / sum;
            for (int i = lane; i < NBc; i += 64) sr[i] *= inv;
        }
    }
    __syncthreads();

    // phase 3: ctx[qi][d] = sum_j p[qi][j] * v[qi+j][d]
    {
        const int d = tid & 63, qb = tid >> 6;
        for (int qi = qb; qi < QT; qi += 4) {
            const float* pr = &ss[qi * NBc];
            float accv = 0.f;
#pragma unroll 4
            for (int j = 0; j < NBc; ++j)
                accv = fmaf(pr[j], kv[(qi + j) * LDK + d], accv);
            ctx[((size_t)(b * Sc + s0 + qi)) * HIDc + h * Dc + d] = accv;
        }
    }
}

// ---------------------------------------------------------------------------
// LayerNorm over last dim (768), block per row
// ---------------------------------------------------------------------------
__global__ __launch_bounds__(256) void ln_kernel(
    const float* __restrict__ y,
    const float* __restrict__ gamma, const float* __restrict__ beta,
    float* __restrict__ out)
{
    const int m = blockIdx.x;
    const float* row = y + (size_t)m * HIDc;
    const int t = threadIdx.x;
    float v0 = row[t], v1 = row[t + 256], v2 = row[t + 512];
    float s = v0 + v1 + v2;
    __shared__ float red[4];
    const int lane = t & 63, wid = t >> 6;
#pragma unroll
    for (int o = 1; o < 64; o <<= 1) s += __shfl_xor(s, o);
    if (lane == 0) red[wid] = s;
    __syncthreads();
    const float mu = (red[0] + red[1] + red[2] + red[3]) * (1.f / HIDc);
    v0 -= mu; v1 -= mu; v2 -= mu;
    float s2 = v0 * v0 + v1 * v1 + v2 * v2;
#pragma unroll
    for (int o = 1; o < 64; o <<= 1) s2 += __shfl_xor(s2, o);
    __syncthreads();
    if (lane == 0) red[wid] = s2;
    __syncthreads();
    const float var = (red[0] + red[1] + red[2] + red[3]) * (1.f / HIDc);
    const float rstd = rsqrtf(var + 1e-12f);
    const size_t base = (size_t)m * HIDc;
    out[base + t]       = v0 * rstd * gamma[t]       + beta[t];
    out[base + t + 256] = v1 * rstd * gamma[t + 256] + beta[t + 256];
    out[base + t + 512] = v2 * rstd * gamma[t + 512] + beta[t + 512];
}

// ---------------------------------------------------------------------------
extern "C" void kernel_launch(void* const* d_in, const int* in_sizes, int n_in,
                              void* d_out, int out_size, void* d_ws, size_t ws_size,
                              hipStream_t stream)
{
    const float* x     = (const float*)d_in[0];
    const float* Wq    = (const float*)d_in[1];
    const float* bq    = (const float*)d_in[2];
    const float* Wk    = (const float*)d_in[3];
    const float* bk    = (const float*)d_in[4];
    const float* Wv    = (const float*)d_in[5];
    const float* bv    = (const float*)d_in[6];
    const float* Wd    = (const float*)d_in[7];
    const float* bd    = (const float*)d_in[8];
    const float* gamma = (const float*)d_in[9];
    const float* beta  = (const float*)d_in[10];
    float* out = (float*)d_out;

    // workspace layout (floats): q,k,v [B,H,S,D]; ctx [B,S,HID]; y [M,HID]
    constexpr size_t CHUNK = (size_t)Bc * Hc * Sc * Dc;  // 6,291,456 floats each
    float* ws  = (float*)d_ws;
    float* qg  = ws;
    float* kg  = qg + CHUNK;
    float* vg  = kg + CHUNK;
    float* ctx = vg + CHUNK;
    float* yws = ctx + CHUNK;
    // total: 5 * 25.17 MB = 125.8 MB of d_ws

    // 1) QKV projections
    gemm_qkv<<<dim3(Mc / 128, HIDc / 128, 3), 256, 0, stream>>>(
        x, Wq, bq, Wk, bk, Wv, bv, qg, kg, vg);

    // 2) banded attention
    constexpr size_t ATTN_LDS = (size_t)(QT * LDK + QT * NBc + KROWS * LDK) * sizeof(float); // 116096
    band_attn<<<dim3(Sc / QT, Hc, Bc), 256, ATTN_LDS, stream>>>(qg, kg, vg, ctx);

    // 3) output projection + residual
    gemm_proj<<<dim3(Mc / 128, HIDc / 128), 256, 0, stream>>>(ctx, Wd, bd, x, yws);

    // 4) LayerNorm
    ln_kernel<<<Mc, 256, 0, stream>>>(yws, gamma, beta, out);
}

// Round 2
// 582.729 us; speedup vs baseline: 2.9805x; 2.9805x over previous
//
#include <hip/hip_runtime.h>
#include <math.h>

typedef unsigned short u16;
typedef short short8 __attribute__((ext_vector_type(8)));
typedef __bf16 bf16x8 __attribute__((ext_vector_type(8)));
typedef float f32x4 __attribute__((ext_vector_type(4)));

// Problem constants
constexpr int Bc   = 2;
constexpr int Sc   = 4096;
constexpr int HIDc = 768;
constexpr int Hc   = 12;
constexpr int Dc   = 64;
constexpr int Wc   = 128;      // band half-width
constexpr int Mc   = Bc * Sc;  // 8192 rows

// attention tiling (MFMA version)
constexpr int QT2  = 64;            // queries per block
constexpr int WIN  = QT2 + 2 * Wc;  // 320 staged window rows
constexpr int NCT  = WIN / 16;      // 20 column tiles
constexpr int LDKW = 72;            // kwin row stride (bf16 elems) — uniform-slot b128 reads
constexpr int LDVT = 328;           // vt row stride
constexpr int LDP  = 328;           // p row stride

// ---------------------------------------------------------------------------
// Fused QKV projection (fp32 compute, bf16 output).
// q,k -> [B,H,S,D]; v -> [B,H,D,S] (transposed for the attention PV stage).
// ---------------------------------------------------------------------------
__global__ __launch_bounds__(256) void gemm_qkv(
    const float* __restrict__ x,
    const float* __restrict__ Wq, const float* __restrict__ bq,
    const float* __restrict__ Wk, const float* __restrict__ bk,
    const float* __restrict__ Wv, const float* __restrict__ bv,
    u16* __restrict__ qg, u16* __restrict__ kg, u16* __restrict__ vtg)
{
    const int z = blockIdx.z;
    const float* Wm   = (z == 0) ? Wq : (z == 1) ? Wk : Wv;
    const float* bias = (z == 0) ? bq : (z == 1) ? bk : bv;
    const float scale = (z == 0) ? 0.125f : 1.0f;  // 1/sqrt(64)

    __shared__ float As[16][132];
    __shared__ float Bs[16][132];

    const int tid = threadIdx.x;
    const int tx = tid & 15, ty = tid >> 4;
    const int m0 = blockIdx.x * 128;
    const int n0 = blockIdx.y * 128;

    float acc[8][8];
#pragma unroll
    for (int i = 0; i < 8; ++i)
#pragma unroll
        for (int j = 0; j < 8; ++j) acc[i][j] = 0.f;

    for (int k0 = 0; k0 < HIDc; k0 += 16) {
        __syncthreads();
#pragma unroll
        for (int l = 0; l < 2; ++l) {
            int q = tid + l * 256;
            int row = q >> 2, kc = (q & 3) * 4;
            float4 v4 = *(const float4*)&x[(size_t)(m0 + row) * HIDc + k0 + kc];
            As[kc + 0][row] = v4.x; As[kc + 1][row] = v4.y;
            As[kc + 2][row] = v4.z; As[kc + 3][row] = v4.w;
        }
#pragma unroll
        for (int l = 0; l < 2; ++l) {
            int q = tid + l * 256;
            int kr = q >> 5, nc = (q & 31) * 4;
            *(float4*)&Bs[kr][nc] = *(const float4*)&Wm[(size_t)(k0 + kr) * HIDc + n0 + nc];
        }
        __syncthreads();
#pragma unroll
        for (int kk = 0; kk < 16; ++kk) {
            float a[8], b[8];
            *(float4*)&a[0] = *(const float4*)&As[kk][ty * 8];
            *(float4*)&a[4] = *(const float4*)&As[kk][ty * 8 + 4];
            *(float4*)&b[0] = *(const float4*)&Bs[kk][tx * 8];
            *(float4*)&b[4] = *(const float4*)&Bs[kk][tx * 8 + 4];
#pragma unroll
            for (int i = 0; i < 8; ++i)
#pragma unroll
                for (int j = 0; j < 8; ++j)
                    acc[i][j] = fmaf(a[i], b[j], acc[i][j]);
        }
    }
#pragma unroll
    for (int i = 0; i < 8; ++i) {
        int m = m0 + ty * 8 + i;
        int b = m >> 12;
        int s = m & (Sc - 1);
#pragma unroll
        for (int j = 0; j < 8; ++j) {
            int n = n0 + tx * 8 + j;
            int h = n >> 6, d = n & 63;
            float val = (acc[i][j] + bias[n]) * scale;
            u16 hv = __builtin_bit_cast(u16, (__bf16)val);
            size_t headbase = ((size_t)(b * Hc + h)) * Sc * Dc;
            if (z == 2)
                vtg[headbase + (size_t)d * Sc + s] = hv;
            else if (z == 1)
                kg[headbase + (size_t)s * Dc + d] = hv;
            else
                qg[headbase + (size_t)s * Dc + d] = hv;
        }
    }
}

// ---------------------------------------------------------------------------
// Output projection + residual: y = ctx @ Wd + bd + x   (fp32)
// ---------------------------------------------------------------------------
__global__ __launch_bounds__(256) void gemm_proj(
    const float* __restrict__ A,
    const float* __restrict__ Wd,
    const float* __restrict__ bd,
    const float* __restrict__ x,
    float* __restrict__ y)
{
    __shared__ float As[16][132];
    __shared__ float Bs[16][132];

    const int tid = threadIdx.x;
    const int tx = tid & 15, ty = tid >> 4;
    const int m0 = blockIdx.x * 128;
    const int n0 = blockIdx.y * 128;

    float acc[8][8];
#pragma unroll
    for (int i = 0; i < 8; ++i)
#pragma unroll
        for (int j = 0; j < 8; ++j) acc[i][j] = 0.f;

    for (int k0 = 0; k0 < HIDc; k0 += 16) {
        __syncthreads();
#pragma unroll
        for (int l = 0; l < 2; ++l) {
            int q = tid + l * 256;
            int row = q >> 2, kc = (q & 3) * 4;
            float4 v4 = *(const float4*)&A[(size_t)(m0 + row) * HIDc + k0 + kc];
            As[kc + 0][row] = v4.x; As[kc + 1][row] = v4.y;
            As[kc + 2][row] = v4.z; As[kc + 3][row] = v4.w;
        }
#pragma unroll
        for (int l = 0; l < 2; ++l) {
            int q = tid + l * 256;
            int kr = q >> 5, nc = (q & 31) * 4;
            *(float4*)&Bs[kr][nc] = *(const float4*)&Wd[(size_t)(k0 + kr) * HIDc + n0 + nc];
        }
        __syncthreads();
#pragma unroll
        for (int kk = 0; kk < 16; ++kk) {
            float a[8], b[8];
            *(float4*)&a[0] = *(const float4*)&As[kk][ty * 8];
            *(float4*)&a[4] = *(const float4*)&As[kk][ty * 8 + 4];
            *(float4*)&b[0] = *(const float4*)&Bs[kk][tx * 8];
            *(float4*)&b[4] = *(const float4*)&Bs[kk][tx * 8 + 4];
#pragma unroll
            for (int i = 0; i < 8; ++i)
#pragma unroll
                for (int j = 0; j < 8; ++j)
                    acc[i][j] = fmaf(a[i], b[j], acc[i][j]);
        }
    }
#pragma unroll
    for (int i = 0; i < 8; ++i) {
        int m = m0 + ty * 8 + i;
#pragma unroll
        for (int j = 0; j < 8; ++j) {
            int n = n0 + tx * 8 + j;
            size_t idx = (size_t)m * HIDc + n;
            y[idx] = acc[i][j] + bd[n] + x[idx];
        }
    }
}

// ---------------------------------------------------------------------------
// MFMA banded attention. Block = (64-query tile, head, batch), 4 waves.
// Wave w owns query strip [w*16, w*16+16). Per strip:
//   S[16][320] = Q_strip[16][64] @ Kwin[320][64]^T     (40 MFMA 16x16x32 bf16)
//   in-register mask + softmax (C/D layout: col=lane&15, row=(lane>>4)*4+reg)
//   P -> LDS bf16, then ctx_strip[16][64] = P[16][320] @ Vwin[320][64] (40 MFMA)
// LDS: kwin[320][72] + vt[64][328] + pm[64][328] = 130048 B
// ---------------------------------------------------------------------------
__global__ __launch_bounds__(256) void band_attn_mfma(
    const u16* __restrict__ qg, const u16* __restrict__ kg,
    const u16* __restrict__ vtg, float* __restrict__ ctx)
{
    extern __shared__ u16 sm[];
    u16* kwin = sm;                      // [WIN][LDKW]
    u16* vt   = kwin + WIN * LDKW;       // [Dc][LDVT]
    u16* pm   = vt + Dc * LDVT;          // [QT2][LDP]

    const int qc = blockIdx.x, h = blockIdx.y, b = blockIdx.z;
    const int s0 = qc * QT2;
    const int tid = threadIdx.x;
    const int lane = tid & 63, wid = tid >> 6;
    const int c16 = lane & 15, g = lane >> 4;
    const size_t hb = ((size_t)(b * Hc + h)) * Sc * Dc;

    // --- fill kwin: 320 rows x 8 16B-segments, zero OOB rows ---
#pragma unroll
    for (int l = 0; l < 10; ++l) {
        int idx = tid + l * 256;            // 0..2559
        int j = idx >> 3, seg = idx & 7;
        int pos = s0 - Wc + j;
        int4 val = make_int4(0, 0, 0, 0);
        if (pos >= 0 && pos < Sc)
            val = *(const int4*)&kg[hb + (size_t)pos * Dc + seg * 8];
        *(int4*)&kwin[j * LDKW + seg * 8] = val;
    }
    // --- fill vt: 64 d-rows x 40 16B-segments along window axis ---
#pragma unroll
    for (int l = 0; l < 10; ++l) {
        int idx = tid + l * 256;            // 0..2559
        int d = idx / 40, seg = idx - d * 40;
        int pos0 = s0 - Wc + seg * 8;       // multiple of 8; never straddles [0,Sc)
        int4 val = make_int4(0, 0, 0, 0);
        if (pos0 >= 0 && pos0 < Sc)
            val = *(const int4*)&vtg[hb + (size_t)d * Sc + pos0];
        *(int4*)&vt[d * LDVT + seg * 8] = val;
    }

    // --- Q fragments for this wave's strip (A-frag: row=lane&15, k=8*(lane>>4)+r) ---
    const u16* qp = &qg[hb + (size_t)(s0 + wid * 16 + c16) * Dc + g * 8];
    bf16x8 qa0 = *(const bf16x8*)qp;          // d 0..31 across k-groups
    bf16x8 qa1 = *(const bf16x8*)(qp + 32);   // d 32..63

    __syncthreads();

    // --- QK^T: 20 col-tiles, K=64 in two K=32 steps ---
    f32x4 acc[NCT];
#pragma unroll
    for (int ct = 0; ct < NCT; ++ct) acc[ct] = (f32x4){0.f, 0.f, 0.f, 0.f};
#pragma unroll
    for (int ct = 0; ct < NCT; ++ct) {
        const u16* kp = &kwin[(ct * 16 + c16) * LDKW + g * 8];
        bf16x8 kb0 = *(const bf16x8*)kp;
        bf16x8 kb1 = *(const bf16x8*)(kp + 32);
        acc[ct] = __builtin_amdgcn_mfma_f32_16x16x32_bf16(qa0, kb0, acc[ct], 0, 0, 0);
        acc[ct] = __builtin_amdgcn_mfma_f32_16x16x32_bf16(qa1, kb1, acc[ct], 0, 0, 0);
    }

    // --- mask + row max (rows live in (reg, lane>>4); cols in lane&15) ---
    float mrow[4] = {-3e38f, -3e38f, -3e38f, -3e38f};
#pragma unroll
    for (int ct = 0; ct < NCT; ++ct) {
#pragma unroll
        for (int r = 0; r < 4; ++r) {
            int rl  = wid * 16 + g * 4 + r;      // query row within 64-tile
            int j   = ct * 16 + c16;             // window offset
            int pos = s0 - Wc + j;               // global key position
            bool valid = (j >= rl) && (j <= rl + 2 * Wc) && (pos >= 0) && (pos < Sc);
            float v = valid ? acc[ct][r] : -3e38f;
            acc[ct][r] = v;
            mrow[r] = fmaxf(mrow[r], v);
        }
    }
#pragma unroll
    for (int r = 0; r < 4; ++r)
#pragma unroll
        for (int off = 1; off < 16; off <<= 1)
            mrow[r] = fmaxf(mrow[r], __shfl_xor(mrow[r], off));

    // --- exp + row sum ---
    float srow[4] = {0.f, 0.f, 0.f, 0.f};
#pragma unroll
    for (int ct = 0; ct < NCT; ++ct)
#pragma unroll
        for (int r = 0; r < 4; ++r) {
            float e = __expf(acc[ct][r] - mrow[r]);
            acc[ct][r] = e;
            srow[r] += e;
        }
#pragma unroll
    for (int r = 0; r < 4; ++r)
#pragma unroll
        for (int off = 1; off < 16; off <<= 1)
            srow[r] += __shfl_xor(srow[r], off);

    // --- P -> LDS (bf16, unnormalized; scale folded into ctx store) ---
#pragma unroll
    for (int ct = 0; ct < NCT; ++ct)
#pragma unroll
        for (int r = 0; r < 4; ++r) {
            int row = wid * 16 + g * 4 + r;
            pm[row * LDP + ct * 16 + c16] = __builtin_bit_cast(u16, (__bf16)acc[ct][r]);
        }
    __syncthreads();

    // --- PV: ctx_strip[16][64] = P_strip[16][320] @ Vwin[320][64] ---
    f32x4 o[4];
#pragma unroll
    for (int dt = 0; dt < 4; ++dt) o[dt] = (f32x4){0.f, 0.f, 0.f, 0.f};
#pragma unroll
    for (int ks = 0; ks < 10; ++ks) {
        bf16x8 pa = *(const bf16x8*)&pm[(wid * 16 + c16) * LDP + ks * 32 + g * 8];
#pragma unroll
        for (int dt = 0; dt < 4; ++dt) {
            bf16x8 vb = *(const bf16x8*)&vt[(dt * 16 + c16) * LDVT + ks * 32 + g * 8];
            o[dt] = __builtin_amdgcn_mfma_f32_16x16x32_bf16(pa, vb, o[dt], 0, 0, 0);
        }
    }

    float inv[4];
#pragma unroll
    for (int r = 0; r < 4; ++r) inv[r] = 1.f / srow[r];
#pragma unroll
    for (int dt = 0; dt < 4; ++dt)
#pragma unroll
        for (int r = 0; r < 4; ++r) {
            int rl = wid * 16 + g * 4 + r;
            ctx[((size_t)(b * Sc + s0 + rl)) * HIDc + h * Dc + dt * 16 + c16] =
                o[dt][r] * inv[r];
        }
}

// ---------------------------------------------------------------------------
// LayerNorm over last dim (768), block per row
// ---------------------------------------------------------------------------
__global__ __launch_bounds__(256) void ln_kernel(
    const float* __restrict__ y,
    const float* __restrict__ gamma, const float* __restrict__ beta,
    float* __restrict__ out)
{
    const int m = blockIdx.x;
    const float* row = y + (size_t)m * HIDc;
    const int t = threadIdx.x;
    float v0 = row[t], v1 = row[t + 256], v2 = row[t + 512];
    float s = v0 + v1 + v2;
    __shared__ float red[4];
    const int lane = t & 63, wid = t >> 6;
#pragma unroll
    for (int o = 1; o < 64; o <<= 1) s += __shfl_xor(s, o);
    if (lane == 0) red[wid] = s;
    __syncthreads();
    const float mu = (red[0] + red[1] + red[2] + red[3]) * (1.f / HIDc);
    v0 -= mu; v1 -= mu; v2 -= mu;
    float s2 = v0 * v0 + v1 * v1 + v2 * v2;
#pragma unroll
    for (int o = 1; o < 64; o <<= 1) s2 += __shfl_xor(s2, o);
    __syncthreads();
    if (lane == 0) red[wid] = s2;
    __syncthreads();
    const float var = (red[0] + red[1] + red[2] + red[3]) * (1.f / HIDc);
    const float rstd = rsqrtf(var + 1e-12f);
    const size_t base = (size_t)m * HIDc;
    out[base + t]       = v0 * rstd * gamma[t]       + beta[t];
    out[base + t + 256] = v1 * rstd * gamma[t + 256] + beta[t + 256];
    out[base + t + 512] = v2 * rstd * gamma[t + 512] + beta[t + 512];
}

// ---------------------------------------------------------------------------
extern "C" void kernel_launch(void* const* d_in, const int* in_sizes, int n_in,
                              void* d_out, int out_size, void* d_ws, size_t ws_size,
                              hipStream_t stream)
{
    const float* x     = (const float*)d_in[0];
    const float* Wq    = (const float*)d_in[1];
    const float* bq    = (const float*)d_in[2];
    const float* Wk    = (const float*)d_in[3];
    const float* bk    = (const float*)d_in[4];
    const float* Wv    = (const float*)d_in[5];
    const float* bv    = (const float*)d_in[6];
    const float* Wd    = (const float*)d_in[7];
    const float* bd    = (const float*)d_in[8];
    const float* gamma = (const float*)d_in[9];
    const float* beta  = (const float*)d_in[10];
    float* out = (float*)d_out;

    // workspace layout: q,k (bf16 [B,H,S,D]); vt (bf16 [B,H,D,S]);
    //                   ctx (fp32 [B,S,HID]); y (fp32 [M,HID])
    constexpr size_t CHUNK = (size_t)Bc * Hc * Sc * Dc;  // 6,291,456 elems
    u16* qg  = (u16*)d_ws;
    u16* kg  = qg + CHUNK;
    u16* vtg = kg + CHUNK;
    float* ctx = (float*)(vtg + CHUNK);
    float* yws = ctx + CHUNK;
    // total: 3*12.58MB + 2*25.17MB = 88.1 MB

    // 1) QKV projections (fp32 -> bf16 out)
    gemm_qkv<<<dim3(Mc / 128, HIDc / 128, 3), 256, 0, stream>>>(
        x, Wq, bq, Wk, bk, Wv, bv, qg, kg, vtg);

    // 2) banded attention (MFMA)
    constexpr size_t ATTN_LDS =
        (size_t)(WIN * LDKW + Dc * LDVT + QT2 * LDP) * sizeof(u16);  // 130048
    band_attn_mfma<<<dim3(Sc / QT2, Hc, Bc), 256, ATTN_LDS, stream>>>(
        qg, kg, vtg, ctx);

    // 3) output projection + residual
    gemm_proj<<<dim3(Mc / 128, HIDc / 128), 256, 0, stream>>>(ctx, Wd, bd, x, yws);

    // 4) LayerNorm
    ln_kernel<<<Mc, 256, 0, stream>>>(yws, gamma, beta, out);
}

// Round 3
// 167.015 us; speedup vs baseline: 10.3994x; 3.4891x over previous
//
#include <hip/hip_runtime.h>
#include <math.h>

typedef unsigned short u16;
typedef __bf16 bf16x8 __attribute__((ext_vector_type(8)));
typedef float f32x4 __attribute__((ext_vector_type(4)));

// Problem constants
constexpr int Bc   = 2;
constexpr int Sc   = 4096;
constexpr int HIDc = 768;
constexpr int Hc   = 12;
constexpr int Dc   = 64;
constexpr int Wc   = 128;
constexpr int Mc   = Bc * Sc;

// attention tiling
constexpr int QT2  = 64;
constexpr int WIN  = QT2 + 2 * Wc;  // 320
constexpr int NCT  = WIN / 16;      // 20
constexpr int LDKW = 72;
constexpr int LDVT = 328;
constexpr int LDP  = 328;

static __device__ __forceinline__ void load_lds16(const void* g, void* l) {
    __builtin_amdgcn_global_load_lds(
        (const __attribute__((address_space(1))) void*)g,
        (__attribute__((address_space(3))) void*)l, 16, 0, 0);
}
static __device__ __forceinline__ u16 to_bf16(float f) {
    return __builtin_bit_cast(u16, (__bf16)f);
}

// ---------------------------------------------------------------------------
// prep: x fp32 -> bf16 (row-major [M][K])
// ---------------------------------------------------------------------------
__global__ __launch_bounds__(256) void prep_x(const float* __restrict__ x,
                                              u16* __restrict__ xb)
{
    int i = blockIdx.x * 256 + threadIdx.x;
    float4 v = ((const float4*)x)[i];
    ushort4 o;
    o.x = to_bf16(v.x); o.y = to_bf16(v.y);
    o.z = to_bf16(v.z); o.w = to_bf16(v.w);
    ((ushort4*)xb)[i] = o;
}

// ---------------------------------------------------------------------------
// prep: transpose W [K][N] fp32 -> Wt [N][K] bf16 (z picks q/k/v/d)
// ---------------------------------------------------------------------------
__global__ __launch_bounds__(256) void prep_w(
    const float* __restrict__ Wq, const float* __restrict__ Wk,
    const float* __restrict__ Wv, const float* __restrict__ Wd,
    u16* __restrict__ wqt, u16* __restrict__ wkt,
    u16* __restrict__ wvt, u16* __restrict__ wdt)
{
    const int z = blockIdx.z;
    const float* W = z == 0 ? Wq : z == 1 ? Wk : z == 2 ? Wv : Wd;
    u16* T         = z == 0 ? wqt : z == 1 ? wkt : z == 2 ? wvt : wdt;

    __shared__ float t[32][33];
    const int bx = blockIdx.x * 32, by = blockIdx.y * 32;
    const int tx = threadIdx.x & 31, ty = threadIdx.x >> 5;
#pragma unroll
    for (int i = 0; i < 32; i += 8)
        t[ty + i][tx] = W[(size_t)(by + ty + i) * HIDc + bx + tx];
    __syncthreads();
#pragma unroll
    for (int i = 0; i < 32; i += 8)
        T[(size_t)(bx + ty + i) * HIDc + by + tx] = to_bf16(t[tx][ty + i]);
}

// ---------------------------------------------------------------------------
// Shared 128x128-tile B^T MFMA GEMM core (K=768, BK=64, XOR-swizzled LDS,
// global_load_lds width 16). acc layout: col=lane&15, row=(lane>>4)*4+r.
// ---------------------------------------------------------------------------
__device__ __forceinline__ void gemm128_bt(
    const u16* __restrict__ A, const u16* __restrict__ Bt,
    int m0, int n0, u16* As, u16* Bs, f32x4 (&acc)[4][4])
{
    const int tid  = threadIdx.x;
    const int lane = tid & 63, wid = tid >> 6;
    const int c16  = lane & 15, g = lane >> 4;
    const int wm   = (wid >> 1) * 64, wn = (wid & 1) * 64;
    const int soff = wid * 4096 + lane * 16;   // byte offset of this wave's issue 0

    for (int k0 = 0; k0 < HIDc; k0 += 64) {
        __syncthreads();
#pragma unroll
        for (int i = 0; i < 4; ++i) {
            int off  = soff + i * 1024;
            int row  = off >> 7;            // 128B per row (64 bf16)
            int slot = (off >> 4) & 7;
            int seg  = slot ^ (row & 7);    // inverse-swizzled global source
            load_lds16(A  + (size_t)(m0 + row) * HIDc + k0 + seg * 8, (char*)As + off);
            load_lds16(Bt + (size_t)(n0 + row) * HIDc + k0 + seg * 8, (char*)Bs + off);
        }
        __syncthreads();
#pragma unroll
        for (int kk = 0; kk < 2; ++kk) {
            bf16x8 af[4], bfr[4];
#pragma unroll
            for (int t = 0; t < 4; ++t) {
                int ar = wm + t * 16 + c16;
                int as = (kk * 4 + g) ^ (ar & 7);
                af[t]  = *(const bf16x8*)(As + ar * 64 + as * 8);
                int br = wn + t * 16 + c16;
                int bs = (kk * 4 + g) ^ (br & 7);
                bfr[t] = *(const bf16x8*)(Bs + br * 64 + bs * 8);
            }
#pragma unroll
            for (int mt = 0; mt < 4; ++mt)
#pragma unroll
                for (int nt = 0; nt < 4; ++nt)
                    acc[mt][nt] = __builtin_amdgcn_mfma_f32_16x16x32_bf16(
                        af[mt], bfr[nt], acc[mt][nt], 0, 0, 0);
        }
    }
}

// ---------------------------------------------------------------------------
// QKV projection: xb[M][K] @ W{q,k,v}t[N][K]^T + bias, q scaled by 1/8.
// q,k -> bf16 [B,H,S,D]; v -> bf16 [B,H,D,S] (packed 4-wide along s).
// ---------------------------------------------------------------------------
__global__ __launch_bounds__(256) void gemm_qkv_mfma(
    const u16* __restrict__ xb,
    const u16* __restrict__ wqt, const u16* __restrict__ wkt,
    const u16* __restrict__ wvt,
    const float* __restrict__ bq, const float* __restrict__ bk,
    const float* __restrict__ bv,
    u16* __restrict__ qg, u16* __restrict__ kg, u16* __restrict__ vtg)
{
    __shared__ u16 As[128 * 64], Bs[128 * 64];
    const int z = blockIdx.z;
    const u16* Bt     = z == 0 ? wqt : z == 1 ? wkt : wvt;
    const float* bias = z == 0 ? bq : z == 1 ? bk : bv;
    const float scale = z == 0 ? 0.125f : 1.0f;
    u16* outqk        = z == 0 ? qg : kg;

    const int m0 = blockIdx.x * 128, n0 = blockIdx.y * 128;
    f32x4 acc[4][4];
#pragma unroll
    for (int i = 0; i < 4; ++i)
#pragma unroll
        for (int j = 0; j < 4; ++j) acc[i][j] = (f32x4){0.f, 0.f, 0.f, 0.f};

    gemm128_bt(xb, Bt, m0, n0, As, Bs, acc);

    const int tid = threadIdx.x, lane = tid & 63, wid = tid >> 6;
    const int c16 = lane & 15, g = lane >> 4;
    const int wm = (wid >> 1) * 64, wn = (wid & 1) * 64;

#pragma unroll
    for (int nt = 0; nt < 4; ++nt) {
        int n = n0 + wn + nt * 16 + c16;
        int h = n >> 6, d = n & 63;
        float bn = bias[n];
#pragma unroll
        for (int mt = 0; mt < 4; ++mt) {
            int m = m0 + wm + mt * 16 + g * 4;
            int b = m >> 12, s = m & (Sc - 1);
            if (z == 2) {
                size_t base = ((size_t)(b * Hc + h)) * Sc * Dc + (size_t)d * Sc + s;
                ushort4 pk;
                pk.x = to_bf16(acc[mt][nt][0] + bn);
                pk.y = to_bf16(acc[mt][nt][1] + bn);
                pk.z = to_bf16(acc[mt][nt][2] + bn);
                pk.w = to_bf16(acc[mt][nt][3] + bn);
                *(ushort4*)&vtg[base] = pk;
            } else {
                size_t base = ((size_t)(b * Hc + h)) * Sc * Dc + (size_t)s * Dc + d;
#pragma unroll
                for (int r = 0; r < 4; ++r)
                    outqk[base + (size_t)r * Dc] =
                        to_bf16((acc[mt][nt][r] + bn) * scale);
            }
        }
    }
}

// ---------------------------------------------------------------------------
// Output projection + residual: y = ctxb @ Wdt^T + bd + x   (fp32 out)
// ---------------------------------------------------------------------------
__global__ __launch_bounds__(256) void gemm_proj_mfma(
    const u16* __restrict__ ctxb, const u16* __restrict__ wdt,
    const float* __restrict__ bd, const float* __restrict__ x,
    float* __restrict__ y)
{
    __shared__ u16 As[128 * 64], Bs[128 * 64];
    const int m0 = blockIdx.x * 128, n0 = blockIdx.y * 128;
    f32x4 acc[4][4];
#pragma unroll
    for (int i = 0; i < 4; ++i)
#pragma unroll
        for (int j = 0; j < 4; ++j) acc[i][j] = (f32x4){0.f, 0.f, 0.f, 0.f};

    gemm128_bt(ctxb, wdt, m0, n0, As, Bs, acc);

    const int tid = threadIdx.x, lane = tid & 63, wid = tid >> 6;
    const int c16 = lane & 15, g = lane >> 4;
    const int wm = (wid >> 1) * 64, wn = (wid & 1) * 64;

#pragma unroll
    for (int nt = 0; nt < 4; ++nt) {
        int n = n0 + wn + nt * 16 + c16;
        float bn = bd[n];
#pragma unroll
        for (int mt = 0; mt < 4; ++mt) {
#pragma unroll
            for (int r = 0; r < 4; ++r) {
                int m = m0 + wm + mt * 16 + g * 4 + r;
                size_t idx = (size_t)m * HIDc + n;
                y[idx] = acc[mt][nt][r] + bn + x[idx];
            }
        }
    }
}

// ---------------------------------------------------------------------------
// MFMA banded attention (unchanged structure; ctx now written bf16).
// ---------------------------------------------------------------------------
__global__ __launch_bounds__(256) void band_attn_mfma(
    const u16* __restrict__ qg, const u16* __restrict__ kg,
    const u16* __restrict__ vtg, u16* __restrict__ ctxb)
{
    extern __shared__ u16 sm[];
    u16* kwin = sm;                      // [WIN][LDKW]
    u16* vt   = kwin + WIN * LDKW;       // [Dc][LDVT]
    u16* pm   = vt + Dc * LDVT;          // [QT2][LDP]

    const int qc = blockIdx.x, h = blockIdx.y, b = blockIdx.z;
    const int s0 = qc * QT2;
    const int tid = threadIdx.x;
    const int lane = tid & 63, wid = tid >> 6;
    const int c16 = lane & 15, g = lane >> 4;
    const size_t hb = ((size_t)(b * Hc + h)) * Sc * Dc;

#pragma unroll
    for (int l = 0; l < 10; ++l) {
        int idx = tid + l * 256;
        int j = idx >> 3, seg = idx & 7;
        int pos = s0 - Wc + j;
        int4 val = make_int4(0, 0, 0, 0);
        if (pos >= 0 && pos < Sc)
            val = *(const int4*)&kg[hb + (size_t)pos * Dc + seg * 8];
        *(int4*)&kwin[j * LDKW + seg * 8] = val;
    }
#pragma unroll
    for (int l = 0; l < 10; ++l) {
        int idx = tid + l * 256;
        int d = idx / 40, seg = idx - d * 40;
        int pos0 = s0 - Wc + seg * 8;
        int4 val = make_int4(0, 0, 0, 0);
        if (pos0 >= 0 && pos0 < Sc)
            val = *(const int4*)&vtg[hb + (size_t)d * Sc + pos0];
        *(int4*)&vt[d * LDVT + seg * 8] = val;
    }

    const u16* qp = &qg[hb + (size_t)(s0 + wid * 16 + c16) * Dc + g * 8];
    bf16x8 qa0 = *(const bf16x8*)qp;
    bf16x8 qa1 = *(const bf16x8*)(qp + 32);

    __syncthreads();

    f32x4 acc[NCT];
#pragma unroll
    for (int ct = 0; ct < NCT; ++ct) acc[ct] = (f32x4){0.f, 0.f, 0.f, 0.f};
#pragma unroll
    for (int ct = 0; ct < NCT; ++ct) {
        const u16* kp = &kwin[(ct * 16 + c16) * LDKW + g * 8];
        bf16x8 kb0 = *(const bf16x8*)kp;
        bf16x8 kb1 = *(const bf16x8*)(kp + 32);
        acc[ct] = __builtin_amdgcn_mfma_f32_16x16x32_bf16(qa0, kb0, acc[ct], 0, 0, 0);
        acc[ct] = __builtin_amdgcn_mfma_f32_16x16x32_bf16(qa1, kb1, acc[ct], 0, 0, 0);
    }

    float mrow[4] = {-3e38f, -3e38f, -3e38f, -3e38f};
#pragma unroll
    for (int ct = 0; ct < NCT; ++ct) {
#pragma unroll
        for (int r = 0; r < 4; ++r) {
            int rl  = wid * 16 + g * 4 + r;
            int j   = ct * 16 + c16;
            int pos = s0 - Wc + j;
            bool valid = (j >= rl) && (j <= rl + 2 * Wc) && (pos >= 0) && (pos < Sc);
            float v = valid ? acc[ct][r] : -3e38f;
            acc[ct][r] = v;
            mrow[r] = fmaxf(mrow[r], v);
        }
    }
#pragma unroll
    for (int r = 0; r < 4; ++r)
#pragma unroll
        for (int off = 1; off < 16; off <<= 1)
            mrow[r] = fmaxf(mrow[r], __shfl_xor(mrow[r], off));

    float srow[4] = {0.f, 0.f, 0.f, 0.f};
#pragma unroll
    for (int ct = 0; ct < NCT; ++ct)
#pragma unroll
        for (int r = 0; r < 4; ++r) {
            float e = __expf(acc[ct][r] - mrow[r]);
            acc[ct][r] = e;
            srow[r] += e;
        }
#pragma unroll
    for (int r = 0; r < 4; ++r)
#pragma unroll
        for (int off = 1; off < 16; off <<= 1)
            srow[r] += __shfl_xor(srow[r], off);

#pragma unroll
    for (int ct = 0; ct < NCT; ++ct)
#pragma unroll
        for (int r = 0; r < 4; ++r) {
            int row = wid * 16 + g * 4 + r;
            pm[row * LDP + ct * 16 + c16] = to_bf16(acc[ct][r]);
        }
    __syncthreads();

    f32x4 o[4];
#pragma unroll
    for (int dt = 0; dt < 4; ++dt) o[dt] = (f32x4){0.f, 0.f, 0.f, 0.f};
#pragma unroll
    for (int ks = 0; ks < 10; ++ks) {
        bf16x8 pa = *(const bf16x8*)&pm[(wid * 16 + c16) * LDP + ks * 32 + g * 8];
#pragma unroll
        for (int dt = 0; dt < 4; ++dt) {
            bf16x8 vb = *(const bf16x8*)&vt[(dt * 16 + c16) * LDVT + ks * 32 + g * 8];
            o[dt] = __builtin_amdgcn_mfma_f32_16x16x32_bf16(pa, vb, o[dt], 0, 0, 0);
        }
    }

    float inv[4];
#pragma unroll
    for (int r = 0; r < 4; ++r) inv[r] = 1.f / srow[r];
#pragma unroll
    for (int dt = 0; dt < 4; ++dt)
#pragma unroll
        for (int r = 0; r < 4; ++r) {
            int rl = wid * 16 + g * 4 + r;
            ctxb[((size_t)(b * Sc + s0 + rl)) * HIDc + h * Dc + dt * 16 + c16] =
                to_bf16(o[dt][r] * inv[r]);
        }
}

// ---------------------------------------------------------------------------
// LayerNorm over last dim (768), block per row
// ---------------------------------------------------------------------------
__global__ __launch_bounds__(256) void ln_kernel(
    const float* __restrict__ y,
    const float* __restrict__ gamma, const float* __restrict__ beta,
    float* __restrict__ out)
{
    const int m = blockIdx.x;
    const float* row = y + (size_t)m * HIDc;
    const int t = threadIdx.x;
    float v0 = row[t], v1 = row[t + 256], v2 = row[t + 512];
    float s = v0 + v1 + v2;
    __shared__ float red[4];
    const int lane = t & 63, wid = t >> 6;
#pragma unroll
    for (int o = 1; o < 64; o <<= 1) s += __shfl_xor(s, o);
    if (lane == 0) red[wid] = s;
    __syncthreads();
    const float mu = (red[0] + red[1] + red[2] + red[3]) * (1.f / HIDc);
    v0 -= mu; v1 -= mu; v2 -= mu;
    float s2 = v0 * v0 + v1 * v1 + v2 * v2;
#pragma unroll
    for (int o = 1; o < 64; o <<= 1) s2 += __shfl_xor(s2, o);
    __syncthreads();
    if (lane == 0) red[wid] = s2;
    __syncthreads();
    const float var = (red[0] + red[1] + red[2] + red[3]) * (1.f / HIDc);
    const float rstd = rsqrtf(var + 1e-12f);
    const size_t base = (size_t)m * HIDc;
    out[base + t]       = v0 * rstd * gamma[t]       + beta[t];
    out[base + t + 256] = v1 * rstd * gamma[t + 256] + beta[t + 256];
    out[base + t + 512] = v2 * rstd * gamma[t + 512] + beta[t + 512];
}

// ---------------------------------------------------------------------------
extern "C" void kernel_launch(void* const* d_in, const int* in_sizes, int n_in,
                              void* d_out, int out_size, void* d_ws, size_t ws_size,
                              hipStream_t stream)
{
    const float* x     = (const float*)d_in[0];
    const float* Wq    = (const float*)d_in[1];
    const float* bq    = (const float*)d_in[2];
    const float* Wk    = (const float*)d_in[3];
    const float* bk    = (const float*)d_in[4];
    const float* Wv    = (const float*)d_in[5];
    const float* bv    = (const float*)d_in[6];
    const float* Wd    = (const float*)d_in[7];
    const float* bd    = (const float*)d_in[8];
    const float* gamma = (const float*)d_in[9];
    const float* beta  = (const float*)d_in[10];
    float* out = (float*)d_out;

    constexpr size_t CHUNK = (size_t)Mc * HIDc;      // 6,291,456
    constexpr size_t WSZ   = (size_t)HIDc * HIDc;    //   589,824
    u16* xb   = (u16*)d_ws;
    u16* wqt  = xb + CHUNK;
    u16* wkt  = wqt + WSZ;
    u16* wvt  = wkt + WSZ;
    u16* wdt  = wvt + WSZ;
    u16* qg   = wdt + WSZ;
    u16* kg   = qg + CHUNK;
    u16* vtg  = kg + CHUNK;
    u16* ctxb = vtg + CHUNK;
    float* yws = (float*)(ctxb + CHUNK);
    // total: (5*CHUNK + 4*WSZ)*2B + CHUNK*4B = 67.6MB + 25.2MB = 92.8MB

    // 0) precision prep
    prep_x<<<(CHUNK / 4) / 256, 256, 0, stream>>>(x, xb);
    prep_w<<<dim3(24, 24, 4), 256, 0, stream>>>(Wq, Wk, Wv, Wd, wqt, wkt, wvt, wdt);

    // 1) QKV projections (bf16 MFMA)
    gemm_qkv_mfma<<<dim3(Mc / 128, HIDc / 128, 3), 256, 0, stream>>>(
        xb, wqt, wkt, wvt, bq, bk, bv, qg, kg, vtg);

    // 2) banded attention (MFMA)
    constexpr size_t ATTN_LDS =
        (size_t)(WIN * LDKW + Dc * LDVT + QT2 * LDP) * sizeof(u16);  // 130048
    band_attn_mfma<<<dim3(Sc / QT2, Hc, Bc), 256, ATTN_LDS, stream>>>(
        qg, kg, vtg, ctxb);

    // 3) output projection + residual (bf16 MFMA, fp32 epilogue)
    gemm_proj_mfma<<<dim3(Mc / 128, HIDc / 128), 256, 0, stream>>>(
        ctxb, wdt, bd, x, yws);

    // 4) LayerNorm
    ln_kernel<<<Mc, 256, 0, stream>>>(yws, gamma, beta, out);
}

// Round 4
// 133.967 us; speedup vs baseline: 12.9648x; 1.2467x over previous
//
#include <hip/hip_runtime.h>
#include <math.h>

typedef unsigned short u16;
typedef __bf16 bf16x8 __attribute__((ext_vector_type(8)));
typedef float f32x4 __attribute__((ext_vector_type(4)));

// Problem constants
constexpr int Bc   = 2;
constexpr int Sc   = 4096;
constexpr int HIDc = 768;
constexpr int Hc   = 12;
constexpr int Dc   = 64;
constexpr int Wc   = 128;
constexpr int Mc   = Bc * Sc;

// attention tiling
constexpr int QT2  = 64;
constexpr int WIN  = QT2 + 2 * Wc;  // 320
constexpr int NCT  = WIN / 16;      // 20

static __device__ __forceinline__ void load_lds16(const void* g, void* l) {
    __builtin_amdgcn_global_load_lds(
        (const __attribute__((address_space(1))) void*)g,
        (__attribute__((address_space(3))) void*)l, 16, 0, 0);
}
static __device__ __forceinline__ u16 to_bf16(float f) {
    return __builtin_bit_cast(u16, (__bf16)f);
}

// ---------------------------------------------------------------------------
// prep: x fp32 -> bf16; block 0 also zero-fills the OOB guard pad.
// ---------------------------------------------------------------------------
__global__ __launch_bounds__(256) void prep_x(const float* __restrict__ x,
                                              u16* __restrict__ xb,
                                              u16* __restrict__ zpad)
{
    int i = blockIdx.x * 256 + threadIdx.x;
    float4 v = ((const float4*)x)[i];
    ushort4 o;
    o.x = to_bf16(v.x); o.y = to_bf16(v.y);
    o.z = to_bf16(v.z); o.w = to_bf16(v.w);
    ((ushort4*)xb)[i] = o;
    if (blockIdx.x == 0 && threadIdx.x < 128)
        ((int4*)zpad)[threadIdx.x] = make_int4(0, 0, 0, 0);  // 2KB zeros
}

// ---------------------------------------------------------------------------
// prep: transpose W [K][N] fp32 -> Wt [N][K] bf16 (z picks q/k/v/d)
// ---------------------------------------------------------------------------
__global__ __launch_bounds__(256) void prep_w(
    const float* __restrict__ Wq, const float* __restrict__ Wk,
    const float* __restrict__ Wv, const float* __restrict__ Wd,
    u16* __restrict__ wqt, u16* __restrict__ wkt,
    u16* __restrict__ wvt, u16* __restrict__ wdt)
{
    const int z = blockIdx.z;
    const float* W = z == 0 ? Wq : z == 1 ? Wk : z == 2 ? Wv : Wd;
    u16* T         = z == 0 ? wqt : z == 1 ? wkt : z == 2 ? wvt : wdt;

    __shared__ float t[32][33];
    const int bx = blockIdx.x * 32, by = blockIdx.y * 32;
    const int tx = threadIdx.x & 31, ty = threadIdx.x >> 5;
#pragma unroll
    for (int i = 0; i < 32; i += 8)
        t[ty + i][tx] = W[(size_t)(by + ty + i) * HIDc + bx + tx];
    __syncthreads();
#pragma unroll
    for (int i = 0; i < 32; i += 8)
        T[(size_t)(bx + ty + i) * HIDc + by + tx] = to_bf16(t[tx][ty + i]);
}

// ---------------------------------------------------------------------------
// Shared 128x128-tile B^T MFMA GEMM core (K=768, BK=64, XOR-swizzled LDS,
// global_load_lds width 16). acc layout: col=lane&15, row=(lane>>4)*4+r.
// ---------------------------------------------------------------------------
__device__ __forceinline__ void gemm128_bt(
    const u16* __restrict__ A, const u16* __restrict__ Bt,
    int m0, int n0, u16* As, u16* Bs, f32x4 (&acc)[4][4])
{
    const int tid  = threadIdx.x;
    const int lane = tid & 63, wid = tid >> 6;
    const int c16  = lane & 15, g = lane >> 4;
    const int wm   = (wid >> 1) * 64, wn = (wid & 1) * 64;
    const int soff = wid * 4096 + lane * 16;

    for (int k0 = 0; k0 < HIDc; k0 += 64) {
        __syncthreads();
#pragma unroll
        for (int i = 0; i < 4; ++i) {
            int off  = soff + i * 1024;
            int row  = off >> 7;
            int slot = (off >> 4) & 7;
            int seg  = slot ^ (row & 7);
            load_lds16(A  + (size_t)(m0 + row) * HIDc + k0 + seg * 8, (char*)As + off);
            load_lds16(Bt + (size_t)(n0 + row) * HIDc + k0 + seg * 8, (char*)Bs + off);
        }
        __syncthreads();
#pragma unroll
        for (int kk = 0; kk < 2; ++kk) {
            bf16x8 af[4], bfr[4];
#pragma unroll
            for (int t = 0; t < 4; ++t) {
                int ar = wm + t * 16 + c16;
                int as = (kk * 4 + g) ^ (ar & 7);
                af[t]  = *(const bf16x8*)(As + ar * 64 + as * 8);
                int br = wn + t * 16 + c16;
                int bs = (kk * 4 + g) ^ (br & 7);
                bfr[t] = *(const bf16x8*)(Bs + br * 64 + bs * 8);
            }
#pragma unroll
            for (int mt = 0; mt < 4; ++mt)
#pragma unroll
                for (int nt = 0; nt < 4; ++nt)
                    acc[mt][nt] = __builtin_amdgcn_mfma_f32_16x16x32_bf16(
                        af[mt], bfr[nt], acc[mt][nt], 0, 0, 0);
        }
    }
}

// ---------------------------------------------------------------------------
// QKV projection: xb[M][K] @ W{q,k,v}t[N][K]^T + bias, q scaled by 1/8.
// q,k -> bf16 [B,H,S,D]; v -> bf16 [B,H,D,S] (packed 4-wide along s).
// ---------------------------------------------------------------------------
__global__ __launch_bounds__(256) void gemm_qkv_mfma(
    const u16* __restrict__ xb,
    const u16* __restrict__ wqt, const u16* __restrict__ wkt,
    const u16* __restrict__ wvt,
    const float* __restrict__ bq, const float* __restrict__ bk,
    const float* __restrict__ bv,
    u16* __restrict__ qg, u16* __restrict__ kg, u16* __restrict__ vtg)
{
    __shared__ u16 As[128 * 64], Bs[128 * 64];
    const int z = blockIdx.z;
    const u16* Bt     = z == 0 ? wqt : z == 1 ? wkt : wvt;
    const float* bias = z == 0 ? bq : z == 1 ? bk : bv;
    const float scale = z == 0 ? 0.125f : 1.0f;
    u16* outqk        = z == 0 ? qg : kg;

    const int m0 = blockIdx.x * 128, n0 = blockIdx.y * 128;
    f32x4 acc[4][4];
#pragma unroll
    for (int i = 0; i < 4; ++i)
#pragma unroll
        for (int j = 0; j < 4; ++j) acc[i][j] = (f32x4){0.f, 0.f, 0.f, 0.f};

    gemm128_bt(xb, Bt, m0, n0, As, Bs, acc);

    const int tid = threadIdx.x, lane = tid & 63, wid = tid >> 6;
    const int c16 = lane & 15, g = lane >> 4;
    const int wm = (wid >> 1) * 64, wn = (wid & 1) * 64;

#pragma unroll
    for (int nt = 0; nt < 4; ++nt) {
        int n = n0 + wn + nt * 16 + c16;
        int h = n >> 6, d = n & 63;
        float bn = bias[n];
#pragma unroll
        for (int mt = 0; mt < 4; ++mt) {
            int m = m0 + wm + mt * 16 + g * 4;
            int b = m >> 12, s = m & (Sc - 1);
            if (z == 2) {
                size_t base = ((size_t)(b * Hc + h)) * Sc * Dc + (size_t)d * Sc + s;
                ushort4 pk;
                pk.x = to_bf16(acc[mt][nt][0] + bn);
                pk.y = to_bf16(acc[mt][nt][1] + bn);
                pk.z = to_bf16(acc[mt][nt][2] + bn);
                pk.w = to_bf16(acc[mt][nt][3] + bn);
                *(ushort4*)&vtg[base] = pk;
            } else {
                size_t base = ((size_t)(b * Hc + h)) * Sc * Dc + (size_t)s * Dc + d;
#pragma unroll
                for (int r = 0; r < 4; ++r)
                    outqk[base + (size_t)r * Dc] =
                        to_bf16((acc[mt][nt][r] + bn) * scale);
            }
        }
    }
}

// ---------------------------------------------------------------------------
// Output projection + residual: y = ctxb @ Wdt^T + bd + x   (fp32 out)
// ---------------------------------------------------------------------------
__global__ __launch_bounds__(256) void gemm_proj_mfma(
    const u16* __restrict__ ctxb, const u16* __restrict__ wdt,
    const float* __restrict__ bd, const float* __restrict__ x,
    float* __restrict__ y)
{
    __shared__ u16 As[128 * 64], Bs[128 * 64];
    const int m0 = blockIdx.x * 128, n0 = blockIdx.y * 128;
    f32x4 acc[4][4];
#pragma unroll
    for (int i = 0; i < 4; ++i)
#pragma unroll
        for (int j = 0; j < 4; ++j) acc[i][j] = (f32x4){0.f, 0.f, 0.f, 0.f};

    gemm128_bt(ctxb, wdt, m0, n0, As, Bs, acc);

    const int tid = threadIdx.x, lane = tid & 63, wid = tid >> 6;
    const int c16 = lane & 15, g = lane >> 4;
    const int wm = (wid >> 1) * 64, wn = (wid & 1) * 64;

#pragma unroll
    for (int nt = 0; nt < 4; ++nt) {
        int n = n0 + wn + nt * 16 + c16;
        float bn = bd[n];
#pragma unroll
        for (int mt = 0; mt < 4; ++mt) {
#pragma unroll
            for (int r = 0; r < 4; ++r) {
                int m = m0 + wm + mt * 16 + g * 4 + r;
                size_t idx = (size_t)m * HIDc + n;
                y[idx] = acc[mt][nt][r] + bn + x[idx];
            }
        }
    }
}

// ---------------------------------------------------------------------------
// MFMA banded attention, v2.
// LDS = kwin[320][64] (40960B, swizzle seg^(row&7))
//     + vt[64][320]   (40960B, swizzle (sl&0x38)|((sl^d)&7))   = 81920 B
// pm[64][320] overlays kwin after the QK barrier (wave-private rows;
// swizzle (sl&0x38)|((sl^q^(q>>3))&7)). 2 blocks/CU.
// Staging via global_load_lds, linear LDS dest + inverse-swizzled global src;
// OOB rows/segs read a zeroed guard pad.
// ---------------------------------------------------------------------------
__global__ __launch_bounds__(256) void band_attn_mfma(
    const u16* __restrict__ qg, const u16* __restrict__ kg,
    const u16* __restrict__ vtg, const u16* __restrict__ zpad,
    u16* __restrict__ ctxb)
{
    extern __shared__ u16 sm[];
    u16* kwin = sm;            // [320][64] u16 (20480)
    u16* vt   = sm + 20480;    // [64][320] u16 (20480)
    u16* pm   = sm;            // [64][320] overlay on kwin after QK

    const int qc = blockIdx.x, h = blockIdx.y, b = blockIdx.z;
    const int s0 = qc * QT2;
    const int tid = threadIdx.x;
    const int lane = tid & 63, wid = tid >> 6;
    const int c16 = lane & 15, g = lane >> 4;
    const size_t hb = ((size_t)(b * Hc + h)) * Sc * Dc;

    // --- stage kwin: 40 chunks x 1KB, wave-striped ---
#pragma unroll
    for (int i = 0; i < 10; ++i) {
        int c   = i * 4 + wid;               // 0..39
        int row = c * 8 + (lane >> 3);       // 0..319
        int seg = (lane & 7) ^ (lane >> 3);  // logical seg at phys slot lane&7
        int pos = s0 - Wc + row;
        const u16* src = (pos >= 0 && pos < Sc)
                       ? &kg[hb + (size_t)pos * Dc + seg * 8] : zpad;
        load_lds16(src, (char*)kwin + c * 1024 + (lane & 63) * 16);
    }
    // --- stage vt: 40 chunks x 1KB ---
#pragma unroll
    for (int i = 0; i < 10; ++i) {
        int c   = i * 4 + wid;
        int idx = c * 64 + lane;             // 16B-unit index 0..2559
        int d   = idx / 40;
        int p   = idx - d * 40;              // phys seg position
        int seg = (p & 0x38) | ((p ^ d) & 7);
        int pos0 = s0 - Wc + seg * 8;
        const u16* src = (pos0 >= 0 && pos0 < Sc)
                       ? &vtg[hb + (size_t)d * Sc + pos0] : zpad;
        load_lds16(src, (char*)vt + idx * 16);
    }

    // --- Q fragments (A-frag: row=lane&15, k=8*(lane>>4)+r) ---
    const u16* qp = &qg[hb + (size_t)(s0 + wid * 16 + c16) * Dc + g * 8];
    bf16x8 qa0 = *(const bf16x8*)qp;
    bf16x8 qa1 = *(const bf16x8*)(qp + 32);

    __syncthreads();

    // --- QK^T: 20 col-tiles, K=64 in two K=32 steps ---
    f32x4 acc[NCT];
#pragma unroll
    for (int ct = 0; ct < NCT; ++ct) acc[ct] = (f32x4){0.f, 0.f, 0.f, 0.f};
    __builtin_amdgcn_s_setprio(1);
#pragma unroll
    for (int ct = 0; ct < NCT; ++ct) {
        int row = ct * 16 + c16;
        const u16* kb = kwin + row * 64;
        bf16x8 kb0 = *(const bf16x8*)(kb + (g       ^ (row & 7)) * 8);
        bf16x8 kb1 = *(const bf16x8*)(kb + ((g + 4) ^ (row & 7)) * 8);
        acc[ct] = __builtin_amdgcn_mfma_f32_16x16x32_bf16(qa0, kb0, acc[ct], 0, 0, 0);
        acc[ct] = __builtin_amdgcn_mfma_f32_16x16x32_bf16(qa1, kb1, acc[ct], 0, 0, 0);
    }
    __builtin_amdgcn_s_setprio(0);

    // --- mask + row max (C layout: row=query=(lane>>4)*4+r, col=window=lane&15) ---
    float mrow[4] = {-3e38f, -3e38f, -3e38f, -3e38f};
#pragma unroll
    for (int ct = 0; ct < NCT; ++ct) {
#pragma unroll
        for (int r = 0; r < 4; ++r) {
            int rl  = wid * 16 + g * 4 + r;
            int j   = ct * 16 + c16;
            int pos = s0 - Wc + j;
            bool valid = (j >= rl) && (j <= rl + 2 * Wc) && (pos >= 0) && (pos < Sc);
            float v = valid ? acc[ct][r] : -3e38f;
            acc[ct][r] = v;
            mrow[r] = fmaxf(mrow[r], v);
        }
    }
#pragma unroll
    for (int r = 0; r < 4; ++r)
#pragma unroll
        for (int off = 1; off < 16; off <<= 1)
            mrow[r] = fmaxf(mrow[r], __shfl_xor(mrow[r], off));

    // --- exp + row sum ---
    float srow[4] = {0.f, 0.f, 0.f, 0.f};
#pragma unroll
    for (int ct = 0; ct < NCT; ++ct)
#pragma unroll
        for (int r = 0; r < 4; ++r) {
            float e = __expf(acc[ct][r] - mrow[r]);
            acc[ct][r] = e;
            srow[r] += e;
        }
#pragma unroll
    for (int r = 0; r < 4; ++r)
#pragma unroll
        for (int off = 1; off < 16; off <<= 1)
            srow[r] += __shfl_xor(srow[r], off);

    // all waves must be done READING kwin before pm overwrites it
    __syncthreads();

    // --- P -> pm (wave-private rows; swizzled scalar writes) ---
#pragma unroll
    for (int ct = 0; ct < NCT; ++ct)
#pragma unroll
        for (int r = 0; r < 4; ++r) {
            int q   = wid * 16 + g * 4 + r;
            int col = ct * 16 + c16;
            int sl  = col >> 3;
            int ph  = (sl & 0x38) | ((sl ^ q ^ (q >> 3)) & 7);
            pm[q * 320 + ph * 8 + (col & 7)] = to_bf16(acc[ct][r]);
        }

    // --- PV: ctx_strip[16][64] = P_strip[16][320] @ Vwin[320][64] ---
    f32x4 o[4];
#pragma unroll
    for (int dt = 0; dt < 4; ++dt) o[dt] = (f32x4){0.f, 0.f, 0.f, 0.f};
    const int qrow = wid * 16 + c16;
    __builtin_amdgcn_s_setprio(1);
#pragma unroll
    for (int ks = 0; ks < 10; ++ks) {
        int sl = ks * 4 + g;
        int ph = (sl & 0x38) | ((sl ^ qrow ^ (qrow >> 3)) & 7);
        bf16x8 pa = *(const bf16x8*)(pm + qrow * 320 + ph * 8);
#pragma unroll
        for (int dt = 0; dt < 4; ++dt) {
            int d  = dt * 16 + c16;
            int pv = (sl & 0x38) | ((sl ^ d) & 7);
            bf16x8 vb = *(const bf16x8*)(vt + d * 320 + pv * 8);
            o[dt] = __builtin_amdgcn_mfma_f32_16x16x32_bf16(pa, vb, o[dt], 0, 0, 0);
        }
    }
    __builtin_amdgcn_s_setprio(0);

    float inv[4];
#pragma unroll
    for (int r = 0; r < 4; ++r) inv[r] = 1.f / srow[r];
#pragma unroll
    for (int dt = 0; dt < 4; ++dt)
#pragma unroll
        for (int r = 0; r < 4; ++r) {
            int rl = wid * 16 + g * 4 + r;
            ctxb[((size_t)(b * Sc + s0 + rl)) * HIDc + h * Dc + dt * 16 + c16] =
                to_bf16(o[dt][r] * inv[r]);
        }
}

// ---------------------------------------------------------------------------
// LayerNorm over last dim (768), block per row
// ---------------------------------------------------------------------------
__global__ __launch_bounds__(256) void ln_kernel(
    const float* __restrict__ y,
    const float* __restrict__ gamma, const float* __restrict__ beta,
    float* __restrict__ out)
{
    const int m = blockIdx.x;
    const float* row = y + (size_t)m * HIDc;
    const int t = threadIdx.x;
    float v0 = row[t], v1 = row[t + 256], v2 = row[t + 512];
    float s = v0 + v1 + v2;
    __shared__ float red[4];
    const int lane = t & 63, wid = t >> 6;
#pragma unroll
    for (int o = 1; o < 64; o <<= 1) s += __shfl_xor(s, o);
    if (lane == 0) red[wid] = s;
    __syncthreads();
    const float mu = (red[0] + red[1] + red[2] + red[3]) * (1.f / HIDc);
    v0 -= mu; v1 -= mu; v2 -= mu;
    float s2 = v0 * v0 + v1 * v1 + v2 * v2;
#pragma unroll
    for (int o = 1; o < 64; o <<= 1) s2 += __shfl_xor(s2, o);
    __syncthreads();
    if (lane == 0) red[wid] = s2;
    __syncthreads();
    const float var = (red[0] + red[1] + red[2] + red[3]) * (1.f / HIDc);
    const float rstd = rsqrtf(var + 1e-12f);
    const size_t base = (size_t)m * HIDc;
    out[base + t]       = v0 * rstd * gamma[t]       + beta[t];
    out[base + t + 256] = v1 * rstd * gamma[t + 256] + beta[t + 256];
    out[base + t + 512] = v2 * rstd * gamma[t + 512] + beta[t + 512];
}

// ---------------------------------------------------------------------------
extern "C" void kernel_launch(void* const* d_in, const int* in_sizes, int n_in,
                              void* d_out, int out_size, void* d_ws, size_t ws_size,
                              hipStream_t stream)
{
    const float* x     = (const float*)d_in[0];
    const float* Wq    = (const float*)d_in[1];
    const float* bq    = (const float*)d_in[2];
    const float* Wk    = (const float*)d_in[3];
    const float* bk    = (const float*)d_in[4];
    const float* Wv    = (const float*)d_in[5];
    const float* bv    = (const float*)d_in[6];
    const float* Wd    = (const float*)d_in[7];
    const float* bd    = (const float*)d_in[8];
    const float* gamma = (const float*)d_in[9];
    const float* beta  = (const float*)d_in[10];
    float* out = (float*)d_out;

    constexpr size_t CHUNK = (size_t)Mc * HIDc;      // 6,291,456
    constexpr size_t WSZ   = (size_t)HIDc * HIDc;    //   589,824
    u16* xb   = (u16*)d_ws;
    u16* wqt  = xb + CHUNK;
    u16* wkt  = wqt + WSZ;
    u16* wvt  = wkt + WSZ;
    u16* wdt  = wvt + WSZ;
    u16* qg   = wdt + WSZ;
    u16* kg   = qg + CHUNK;
    u16* vtg  = kg + CHUNK;
    u16* ctxb = vtg + CHUNK;
    float* yws = (float*)(ctxb + CHUNK);
    u16* zpad  = (u16*)(yws + CHUNK);   // 2KB zero guard (filled by prep_x)

    // 0) precision prep (+ zero guard fill)
    prep_x<<<(CHUNK / 4) / 256, 256, 0, stream>>>(x, xb, zpad);
    prep_w<<<dim3(24, 24, 4), 256, 0, stream>>>(Wq, Wk, Wv, Wd, wqt, wkt, wvt, wdt);

    // 1) QKV projections (bf16 MFMA)
    gemm_qkv_mfma<<<dim3(Mc / 128, HIDc / 128, 3), 256, 0, stream>>>(
        xb, wqt, wkt, wvt, bq, bk, bv, qg, kg, vtg);

    // 2) banded attention (MFMA, 80KB LDS -> 2 blocks/CU)
    band_attn_mfma<<<dim3(Sc / QT2, Hc, Bc), 256, 81920, stream>>>(
        qg, kg, vtg, zpad, ctxb);

    // 3) output projection + residual (bf16 MFMA, fp32 epilogue)
    gemm_proj_mfma<<<dim3(Mc / 128, HIDc / 128), 256, 0, stream>>>(
        ctxb, wdt, bd, x, yws);

    // 4) LayerNorm
    ln_kernel<<<Mc, 256, 0, stream>>>(yws, gamma, beta, out);
}